// Round 6
// baseline (37.437 us; speedup 1.0000x reference)
//
#include <hip/hip_runtime.h>
#include <stdint.h>

// SNN 50-step integrate-fire spike encoding.
// x: [256,1,4096] f32 -> out: [256,1,4096,50] f32 (0/1 spikes).
// Pure HBM-write-bound: 204.8 MB out @ ~6.9 TB/s fill-rate => ~30 us floor.
//
// R5 post-mortem: block-wide double-buffered LDS + single-barrier pipelining
// failed correctness (race signature). This version is race-free BY
// CONSTRUCTION: no LDS, no __syncthreads. Each WAVE owns 256 elements in 4
// chunks of 64 (1 elem/lane). Spike masks live in registers; the coalesced
// writeout fetches other lanes' masks via __shfl (register exchange, no
// ordering hazards). Chunk c+1's pure-register recurrence overlaps chunk c's
// fire-and-forget store drain; waves are fully independent.
//
// Writeout per chunk: 64 elems * 50 floats = 3200 floats = 1600 f32x2 pairs
// / 64 lanes = exactly 25 iterations, no tail. A pair never straddles an
// element boundary (2k+1 is odd; boundaries are multiples of 50), so one
// 64-bit shuffle serves both floats of the pair.
// Plain stores, NOT nontemporal (R2: `nt` loses L2 write-combining,
// 5.9 -> 4.5 TB/s regression).

#define TIME 50
#define BLOCK 256
#define WARP 64
#define CHUNKS 4
#define EPW (CHUNKS * WARP)          // 256 elements per wave
#define EPB ((BLOCK / WARP) * EPW)   // 1024 elements per block

typedef float f32x2 __attribute__((ext_vector_type(2)));

__global__ __launch_bounds__(BLOCK) void snn_encode_kernel(
    const float* __restrict__ x, float* __restrict__ out, int n_elems) {
    const int lane = threadIdx.x & (WARP - 1);
    const int wid = threadIdx.x >> 6;
    const int wbase = blockIdx.x * EPB + wid * EPW;  // wave's first element

    // Prefetch the 4 chunk inputs (coalesced within wave: 64 consecutive).
    float cur[CHUNKS];
    #pragma unroll
    for (int c = 0; c < CHUNKS; ++c) {
        const int elem = wbase + c * WARP + lane;
        cur[c] = (elem < n_elems) ? (x[elem] * 1.0f + 1.0f) : 0.0f;
    }

    #pragma unroll
    for (int c = 0; c < CHUNKS; ++c) {
        // ---- compute: 50-step recurrence, exact reference f32 semantics ----
        unsigned long long bits = 0ull;
        {
            float v = 0.0f;
            float th = 0.5f;                  // THRESH_ENC
            #pragma unroll
            for (int t = 0; t < TIME; ++t) {
                v += cur[c];                  // integrate
                if (v >= th) {                // fire
                    v = 0.0f;                 // reset (leak = 1.0)
                    th += 0.03f;              // THRESH_PLUS adaptation
                    bits |= (1ull << t);
                }
            }
        }

        // ---- writeout: coalesced f32x2 via wave shuffle, 25 exact iters ----
        float* cdst = out + (size_t)(wbase + c * WARP) * TIME;
        #pragma unroll 5
        for (int it = 0; it < 25; ++it) {
            const int k = it * WARP + lane;   // pair index in chunk [0,1600)
            const int e = k / 25;             // source lane (element in chunk)
            const int t2 = (k - e * 25) * 2;  // first bit of the pair
            const unsigned long long b = __shfl(bits, e, WARP);
            f32x2 vals;
            vals.x = (float)((b >> t2) & 1ull);
            vals.y = (float)((b >> (t2 + 1)) & 1ull);
            *reinterpret_cast<f32x2*>(cdst + k * 2) = vals;
        }
    }
}

extern "C" void kernel_launch(void* const* d_in, const int* in_sizes, int n_in,
                              void* d_out, int out_size, void* d_ws, size_t ws_size,
                              hipStream_t stream) {
    const float* x = (const float*)d_in[0];
    float* out = (float*)d_out;
    const int n = in_sizes[0];               // 256*1*4096 = 1,048,576 elements
    const int blocks = (n + EPB - 1) / EPB;  // 1024
    snn_encode_kernel<<<blocks, BLOCK, 0, stream>>>(x, out, n);
}